// Round 1
// baseline (334.803 us; speedup 1.0000x reference)
//
#include <hip/hip_runtime.h>
#include <hip/hip_bf16.h>

typedef __attribute__((ext_vector_type(8))) short short8;
typedef __attribute__((ext_vector_type(4))) float f32x4;

#define T_PRE 64
#define T_FWD 80
#define BATCHN 4096

#define HP 264   // h row pitch (bf16 elems): 256 + 8 pad
#define IP 136   // input row pitch: 128 + 8 pad

// ---- ws layout (ushort offsets) ----
// wrnn [256][384] bf16 : rows j = [W_hh[j][0..255] | W_ih[j][0..127]]
// wss  [256][320] bf16 : rows j = [A_w[j][0..255]  | B_w[j][0..63]]
// c    [64][256]  bf16 : C_w
// then floats: brnn[256] = b_ih+b_hh, bss[256] = A_b+B_b
#define U_WRNN 0
#define U_WSS  98304
#define U_C    180224
#define U_END  196608
#define PREP_N 197120

__device__ __forceinline__ unsigned short bf1(float a) {
  unsigned ua = __float_as_uint(a);
  return (unsigned short)((ua + 0x7fffu + ((ua >> 16) & 1u)) >> 16);
}
__device__ __forceinline__ unsigned pk(float a, float b) {
  __hip_bfloat162 h = __float22bfloat162_rn(make_float2(a, b));
  unsigned u;
  __builtin_memcpy(&u, &h, 4);
  return u;
}
__device__ __forceinline__ float tanh_fast(float x) {
  float e = __expf(2.0f * x);  // saturates correctly for large |x|
  return 1.0f - 2.0f * __builtin_amdgcn_rcpf(e + 1.0f);
}

__global__ void prep_kernel(const float* __restrict__ A_w, const float* __restrict__ A_b,
                            const float* __restrict__ B_w, const float* __restrict__ B_b,
                            const float* __restrict__ C_w,
                            const float* __restrict__ W_ih, const float* __restrict__ b_ih,
                            const float* __restrict__ W_hh, const float* __restrict__ b_hh,
                            unsigned short* __restrict__ ws) {
  int i = blockIdx.x * 256 + threadIdx.x;
  if (i < U_WSS) {
    int j = i / 384, k = i - j * 384;
    float v = (k < 256) ? W_hh[j * 256 + k] : W_ih[j * 128 + (k - 256)];
    ws[i] = bf1(v);
  } else if (i < U_C) {
    int ii = i - U_WSS;
    int j = ii / 320, k = ii - j * 320;
    float v = (k < 256) ? A_w[j * 256 + k] : B_w[j * 64 + (k - 256)];
    ws[i] = bf1(v);
  } else if (i < U_END) {
    int ii = i - U_C;
    int o = ii >> 8, k = ii & 255;
    ws[i] = bf1(C_w[o * 256 + k]);
  } else if (i < PREP_N) {
    float* fb = (float*)(ws + U_END);
    int j = i - U_END;
    fb[j] = (j < 256) ? (b_ih[j] + b_hh[j]) : (A_b[j - 256] + B_b[j - 256]);
  }
}

// Persistent: 256 blocks x 16 batch rows, 256 threads (4 waves, 1/SIMD).
// Wave w owns states [w*64, w*64+64) (mt=4)  ->  LDS h-read redundancy 4x (was 8x).
// Per-SIMD MFMA work unchanged (1 wave x 48 = 2 waves x 24); LDS reads halved.
// Double-buffered h + inputs -> 1 barrier/step.
__global__ __launch_bounds__(256, 1) void rnn_ss_kernel(
    const float* __restrict__ pre_x, const float* __restrict__ pre_y,
    const float* __restrict__ fwd_x, const float* __restrict__ C_b,
    const unsigned short* __restrict__ ws, float* __restrict__ out) {
  __shared__ unsigned short hbuf[2][16 * HP];
  __shared__ unsigned short ibuf[2][16 * IP];

  const int tid = threadIdx.x;
  const int lane = tid & 63;
  const int w = tid >> 6;      // wave 0..3
  const int col = lane & 15;   // batch col (B/D)
  const int q = lane >> 4;     // quad
  const int r0 = blockIdx.x * 16;
  const int srow = tid >> 4;   // staging batch row 0..15
  const int sc4 = tid & 15;    // staging float4 col 0..15

  // zero hbuf[0] h region (16 rows x 256 elems) -> h0 = 0
#pragma unroll
  for (int it = 0; it < 4; ++it) {
    int i = tid + it * 256;
    int r = i >> 6, c = (i & 63) * 4;
    *(uint2*)&hbuf[0][r * HP + c] = make_uint2(0u, 0u);
  }

  const float* fbias = (const float*)(ws + U_END);
  int cur = 0;

  // ---------------- encoder tanh-RNN (K = 384) ----------------
  {
    short8 wf[4][12];
#pragma unroll
    for (int mt = 0; mt < 4; ++mt)
#pragma unroll
      for (int kf = 0; kf < 12; ++kf)
        wf[mt][kf] = *(const short8*)(ws + U_WRNN +
                       (size_t)(w * 64 + mt * 16 + col) * 384 + kf * 32 + q * 8);
    f32x4 br[4];
#pragma unroll
    for (int mt = 0; mt < 4; ++mt)
      br[mt] = *(const f32x4*)(fbias + w * 64 + mt * 16 + q * 4);

    // stage xy_0 into ibuf[0] (each thread: one f32x4 of x and one of y)
    {
      f32x4 vx = *(const f32x4*)(pre_x + (size_t)(r0 + srow) * 64 + sc4 * 4);
      f32x4 vy = *(const f32x4*)(pre_y + (size_t)(r0 + srow) * 64 + sc4 * 4);
      *(uint2*)&ibuf[0][srow * IP + sc4 * 4] =
          make_uint2(pk(vx[0], vx[1]), pk(vx[2], vx[3]));
      *(uint2*)&ibuf[0][srow * IP + 64 + sc4 * 4] =
          make_uint2(pk(vy[0], vy[1]), pk(vy[2], vy[3]));
    }

    for (int t = 0; t < T_PRE; ++t) {
      f32x4 nvx, nvy;
      const bool sy = (t < T_PRE - 1);
      if (sy) {
        nvx = *(const f32x4*)(pre_x + ((size_t)(t + 1) * BATCHN + r0 + srow) * 64 + sc4 * 4);
        nvy = *(const f32x4*)(pre_y + ((size_t)(t + 1) * BATCHN + r0 + srow) * 64 + sc4 * 4);
      } else {
        nvx = *(const f32x4*)(fwd_x + (size_t)(r0 + srow) * 64 + sc4 * 4);  // fwd_x[0]
      }
      __syncthreads();  // h_t (hbuf[cur]) and xy_t (ibuf[cur]) visible
      const unsigned short* hc = hbuf[cur];
      const unsigned short* ic = ibuf[cur];
      short8 bfr[12];
#pragma unroll
      for (int kf = 0; kf < 8; ++kf)
        bfr[kf] = *(const short8*)&hc[col * HP + kf * 32 + q * 8];
#pragma unroll
      for (int kf = 8; kf < 12; ++kf)
        bfr[kf] = *(const short8*)&ic[col * IP + (kf - 8) * 32 + q * 8];
      f32x4 acc[4];
#pragma unroll
      for (int mt = 0; mt < 4; ++mt) acc[mt] = br[mt];
#pragma unroll
      for (int kf = 0; kf < 12; ++kf)
#pragma unroll
        for (int mt = 0; mt < 4; ++mt)
          acc[mt] = __builtin_amdgcn_mfma_f32_16x16x32_bf16(wf[mt][kf], bfr[kf], acc[mt], 0, 0, 0);
      unsigned short* hn_ = hbuf[cur ^ 1];
#pragma unroll
      for (int mt = 0; mt < 4; ++mt) {
        float t0 = tanh_fast(acc[mt][0]), t1 = tanh_fast(acc[mt][1]);
        float t2 = tanh_fast(acc[mt][2]), t3 = tanh_fast(acc[mt][3]);
        *(uint2*)&hn_[col * HP + w * 64 + mt * 16 + q * 4] =
            make_uint2(pk(t0, t1), pk(t2, t3));
      }
      *(uint2*)&ibuf[cur ^ 1][srow * IP + sc4 * 4] =
          make_uint2(pk(nvx[0], nvx[1]), pk(nvx[2], nvx[3]));
      if (sy)
        *(uint2*)&ibuf[cur ^ 1][srow * IP + 64 + sc4 * 4] =
            make_uint2(pk(nvy[0], nvy[1]), pk(nvy[2], nvy[3]));
      cur ^= 1;
    }
  }

  // ---------------- state-space rollout (K = 320) + fused y = C h ----------------
  {
    short8 sf[4][10];
#pragma unroll
    for (int mt = 0; mt < 4; ++mt)
#pragma unroll
      for (int kf = 0; kf < 10; ++kf)
        sf[mt][kf] = *(const short8*)(ws + U_WSS +
                       (size_t)(w * 64 + mt * 16 + col) * 320 + kf * 32 + q * 8);
    f32x4 bs[4];
#pragma unroll
    for (int mt = 0; mt < 4; ++mt)
      bs[mt] = *(const f32x4*)(fbias + 256 + w * 64 + mt * 16 + q * 4);
    short8 cf[8];
#pragma unroll
    for (int kf = 0; kf < 8; ++kf)
      cf[kf] = *(const short8*)(ws + U_C + (size_t)(w * 16 + col) * 256 + kf * 32 + q * 8);
    f32x4 cb = *(const f32x4*)(C_b + w * 16 + q * 4);

    for (int i = 0; i < T_FWD; ++i) {
      f32x4 nv;
      if (i < T_FWD - 1)
        nv = *(const f32x4*)(fwd_x + ((size_t)(i + 1) * BATCHN + r0 + srow) * 64 + sc4 * 4);
      __syncthreads();  // h_i (hbuf[cur]) and x_i (ibuf[cur]) visible
      const unsigned short* hc = hbuf[cur];
      const unsigned short* ic = ibuf[cur];
      short8 bfr[10];
#pragma unroll
      for (int kf = 0; kf < 8; ++kf)
        bfr[kf] = *(const short8*)&hc[col * HP + kf * 32 + q * 8];
#pragma unroll
      for (int kf = 8; kf < 10; ++kf)
        bfr[kf] = *(const short8*)&ic[col * IP + (kf - 8) * 32 + q * 8];
      f32x4 acc[4];
#pragma unroll
      for (int mt = 0; mt < 4; ++mt) acc[mt] = bs[mt];
#pragma unroll
      for (int kf = 0; kf < 10; ++kf)
#pragma unroll
        for (int mt = 0; mt < 4; ++mt)
          acc[mt] = __builtin_amdgcn_mfma_f32_16x16x32_bf16(sf[mt][kf], bfr[kf], acc[mt], 0, 0, 0);
      if (i >= 1) {  // y_i = C h_i + C_b (h_i = this step's B-frags); 16 rows per wave
        f32x4 y = cb;
#pragma unroll
        for (int kf = 0; kf < 8; ++kf)
          y = __builtin_amdgcn_mfma_f32_16x16x32_bf16(cf[kf], bfr[kf], y, 0, 0, 0);
        *(f32x4*)(out + ((size_t)(i - 1) * BATCHN + r0 + col) * 64 + w * 16 + q * 4) = y;
      }
      unsigned short* hn_ = hbuf[cur ^ 1];
#pragma unroll
      for (int mt = 0; mt < 4; ++mt)
        *(uint2*)&hn_[col * HP + w * 64 + mt * 16 + q * 4] =
            make_uint2(pk(acc[mt][0], acc[mt][1]), pk(acc[mt][2], acc[mt][3]));
      if (i < T_FWD - 1)
        *(uint2*)&ibuf[cur ^ 1][srow * IP + sc4 * 4] =
            make_uint2(pk(nv[0], nv[1]), pk(nv[2], nv[3]));
      cur ^= 1;
    }

    // epilogue: y_80 from h_80
    __syncthreads();
    {
      const unsigned short* hc = hbuf[cur];
      short8 bfr[8];
#pragma unroll
      for (int kf = 0; kf < 8; ++kf)
        bfr[kf] = *(const short8*)&hc[col * HP + kf * 32 + q * 8];
      f32x4 y = cb;
#pragma unroll
      for (int kf = 0; kf < 8; ++kf)
        y = __builtin_amdgcn_mfma_f32_16x16x32_bf16(cf[kf], bfr[kf], y, 0, 0, 0);
      *(f32x4*)(out + ((size_t)(T_FWD - 1) * BATCHN + r0 + col) * 64 + w * 16 + q * 4) = y;
    }
  }
}

extern "C" void kernel_launch(void* const* d_in, const int* in_sizes, int n_in,
                              void* d_out, int out_size, void* d_ws, size_t ws_size,
                              hipStream_t stream) {
  const float* pre_x = (const float*)d_in[0];
  const float* pre_y = (const float*)d_in[1];
  const float* fwd_x = (const float*)d_in[2];
  const float* A_w   = (const float*)d_in[3];
  const float* A_b   = (const float*)d_in[4];
  const float* B_w   = (const float*)d_in[5];
  const float* B_b   = (const float*)d_in[6];
  const float* C_w   = (const float*)d_in[7];
  const float* C_b   = (const float*)d_in[8];
  const float* W_ih  = (const float*)d_in[9];
  const float* b_ih  = (const float*)d_in[10];
  const float* W_hh  = (const float*)d_in[11];
  const float* b_hh  = (const float*)d_in[12];
  unsigned short* ws = (unsigned short*)d_ws;
  float* out = (float*)d_out;

  prep_kernel<<<(PREP_N + 255) / 256, 256, 0, stream>>>(
      A_w, A_b, B_w, B_b, C_w, W_ih, b_ih, W_hh, b_hh, ws);
  rnn_ss_kernel<<<BATCHN / 16, 256, 0, stream>>>(pre_x, pre_y, fwd_x, C_b, ws, out);
}

// Round 2
// 323.152 us; speedup vs baseline: 1.0361x; 1.0361x over previous
//
#include <hip/hip_runtime.h>
#include <hip/hip_bf16.h>

typedef __attribute__((ext_vector_type(8))) short short8;
typedef __attribute__((ext_vector_type(4))) float f32x4;

#define T_PRE 64
#define T_FWD 80
#define BATCHN 4096

#define HP 264   // h row pitch (bf16 elems): 256 + 8 pad
#define IP 136   // input row pitch: 128 + 8 pad

// ---- ws layout (ushort offsets) ----
// wrnn [256][384] bf16 : rows j = [W_hh[j][0..255] | W_ih[j][0..127]]
// wss  [256][320] bf16 : rows j = [A_w[j][0..255]  | B_w[j][0..63]]
// c    [64][256]  bf16 : C_w
// then floats: brnn[256] = b_ih+b_hh, bss[256] = A_b+B_b
#define U_WRNN 0
#define U_WSS  98304
#define U_C    180224
#define U_END  196608
#define PREP_N 197120

__device__ __forceinline__ unsigned short bf1(float a) {
  unsigned ua = __float_as_uint(a);
  return (unsigned short)((ua + 0x7fffu + ((ua >> 16) & 1u)) >> 16);
}
__device__ __forceinline__ unsigned pk(float a, float b) {
  __hip_bfloat162 h = __float22bfloat162_rn(make_float2(a, b));
  unsigned u;
  __builtin_memcpy(&u, &h, 4);
  return u;
}
__device__ __forceinline__ float tanh_fast(float x) {
  float e = __expf(2.0f * x);  // saturates correctly for large |x|
  return 1.0f - 2.0f * __builtin_amdgcn_rcpf(e + 1.0f);
}

__global__ void prep_kernel(const float* __restrict__ A_w, const float* __restrict__ A_b,
                            const float* __restrict__ B_w, const float* __restrict__ B_b,
                            const float* __restrict__ C_w,
                            const float* __restrict__ W_ih, const float* __restrict__ b_ih,
                            const float* __restrict__ W_hh, const float* __restrict__ b_hh,
                            unsigned short* __restrict__ ws) {
  int i = blockIdx.x * 256 + threadIdx.x;
  if (i < U_WSS) {
    int j = i / 384, k = i - j * 384;
    float v = (k < 256) ? W_hh[j * 256 + k] : W_ih[j * 128 + (k - 256)];
    ws[i] = bf1(v);
  } else if (i < U_C) {
    int ii = i - U_WSS;
    int j = ii / 320, k = ii - j * 320;
    float v = (k < 256) ? A_w[j * 256 + k] : B_w[j * 64 + (k - 256)];
    ws[i] = bf1(v);
  } else if (i < U_END) {
    int ii = i - U_C;
    int o = ii >> 8, k = ii & 255;
    ws[i] = bf1(C_w[o * 256 + k]);
  } else if (i < PREP_N) {
    float* fb = (float*)(ws + U_END);
    int j = i - U_END;
    fb[j] = (j < 256) ? (b_ih[j] + b_hh[j]) : (A_b[j - 256] + B_b[j - 256]);
  }
}

// Persistent: 256 blocks x 16 batch rows, 512 threads (8 waves, 2/SIMD).
// Wave w owns states [w*32, w*32+32). Double-buffered h + inputs -> 1 barrier/step.
// KEY FIX vs prior rounds: global prefetch for step t+1 is issued AFTER the
// step's __syncthreads(), so the compiler's vmcnt(0)-drain-before-s_barrier no
// longer puts global-load latency on the serial critical path; the load's
// latency hides under the ~930cy MFMA phase and is consumed (ds_write) at the
// step's end.
__global__ __launch_bounds__(512, 1) void rnn_ss_kernel(
    const float* __restrict__ pre_x, const float* __restrict__ pre_y,
    const float* __restrict__ fwd_x, const float* __restrict__ C_b,
    const unsigned short* __restrict__ ws, float* __restrict__ out) {
  __shared__ unsigned short hbuf[2][16 * HP];
  __shared__ unsigned short ibuf[2][16 * IP];

  const int tid = threadIdx.x;
  const int lane = tid & 63;
  const int w = tid >> 6;      // wave 0..7
  const int col = lane & 15;   // batch col (B/D) / A row-in-tile
  const int q = lane >> 4;     // quad
  const int r0 = blockIdx.x * 16;
  const int srow = (tid & 255) >> 4;  // staging batch row 0..15
  const int sc4 = tid & 15;           // staging float4 col 0..15
  const bool xhalf = (tid >= 256);    // waves 4-7 stage x; waves 0-3 stage y (RNN)

  // zero hbuf[0] h region (16 rows x 256 elems) -> h0 = 0
#pragma unroll
  for (int it = 0; it < 2; ++it) {
    int i = tid + it * 512;
    int r = i >> 6, c = (i & 63) * 4;
    *(uint2*)&hbuf[0][r * HP + c] = make_uint2(0u, 0u);
  }

  const float* fbias = (const float*)(ws + U_END);
  int cur = 0;

  // ---------------- encoder tanh-RNN (K = 384) ----------------
  {
    short8 wf[2][12];
#pragma unroll
    for (int mt = 0; mt < 2; ++mt)
#pragma unroll
      for (int kf = 0; kf < 12; ++kf)
        wf[mt][kf] = *(const short8*)(ws + U_WRNN +
                       (size_t)(w * 32 + mt * 16 + col) * 384 + kf * 32 + q * 8);
    f32x4 br[2];
#pragma unroll
    for (int mt = 0; mt < 2; ++mt)
      br[mt] = *(const f32x4*)(fbias + w * 32 + mt * 16 + q * 4);

    // stage xy_0 into ibuf[0]
    {
      f32x4 v = xhalf ? *(const f32x4*)(pre_x + (size_t)(r0 + srow) * 64 + sc4 * 4)
                      : *(const f32x4*)(pre_y + (size_t)(r0 + srow) * 64 + sc4 * 4);
      *(uint2*)&ibuf[0][srow * IP + (xhalf ? 0 : 64) + sc4 * 4] =
          make_uint2(pk(v[0], v[1]), pk(v[2], v[3]));
    }

    for (int t = 0; t < T_PRE; ++t) {
      __syncthreads();  // h_t (hbuf[cur]) and xy_t (ibuf[cur]) visible
      // issue next-step prefetch AFTER the barrier -> latency hides under MFMAs
      f32x4 nv;
      bool do_stage = true;
      if (t < T_PRE - 1) {
        nv = xhalf ? *(const f32x4*)(pre_x + ((size_t)(t + 1) * BATCHN + r0 + srow) * 64 + sc4 * 4)
                   : *(const f32x4*)(pre_y + ((size_t)(t + 1) * BATCHN + r0 + srow) * 64 + sc4 * 4);
      } else if (xhalf) {
        nv = *(const f32x4*)(fwd_x + (size_t)(r0 + srow) * 64 + sc4 * 4);  // fwd_x[0]
      } else {
        do_stage = false;
      }
      const unsigned short* hc = hbuf[cur];
      const unsigned short* ic = ibuf[cur];
      short8 bfr[12];
#pragma unroll
      for (int kf = 0; kf < 8; ++kf)
        bfr[kf] = *(const short8*)&hc[col * HP + kf * 32 + q * 8];
#pragma unroll
      for (int kf = 8; kf < 12; ++kf)
        bfr[kf] = *(const short8*)&ic[col * IP + (kf - 8) * 32 + q * 8];
      f32x4 acc[2];
#pragma unroll
      for (int mt = 0; mt < 2; ++mt) acc[mt] = br[mt];
#pragma unroll
      for (int kf = 0; kf < 12; ++kf)
#pragma unroll
        for (int mt = 0; mt < 2; ++mt)
          acc[mt] = __builtin_amdgcn_mfma_f32_16x16x32_bf16(wf[mt][kf], bfr[kf], acc[mt], 0, 0, 0);
      unsigned short* hn_ = hbuf[cur ^ 1];
#pragma unroll
      for (int mt = 0; mt < 2; ++mt) {
        float t0 = tanh_fast(acc[mt][0]), t1 = tanh_fast(acc[mt][1]);
        float t2 = tanh_fast(acc[mt][2]), t3 = tanh_fast(acc[mt][3]);
        *(uint2*)&hn_[col * HP + w * 32 + mt * 16 + q * 4] =
            make_uint2(pk(t0, t1), pk(t2, t3));
      }
      if (do_stage)
        *(uint2*)&ibuf[cur ^ 1][srow * IP + (xhalf ? 0 : 64) + sc4 * 4] =
            make_uint2(pk(nv[0], nv[1]), pk(nv[2], nv[3]));
      cur ^= 1;
    }
  }

  // ---------------- state-space rollout (K = 320) + fused y = C h ----------------
  {
    short8 sf[2][10];
#pragma unroll
    for (int mt = 0; mt < 2; ++mt)
#pragma unroll
      for (int kf = 0; kf < 10; ++kf)
        sf[mt][kf] = *(const short8*)(ws + U_WSS +
                       (size_t)(w * 32 + mt * 16 + col) * 320 + kf * 32 + q * 8);
    f32x4 bs[2];
#pragma unroll
    for (int mt = 0; mt < 2; ++mt)
      bs[mt] = *(const f32x4*)(fbias + 256 + w * 32 + mt * 16 + q * 4);
    short8 cf[8];
    f32x4 cb;
    if (w < 4) {
#pragma unroll
      for (int kf = 0; kf < 8; ++kf)
        cf[kf] = *(const short8*)(ws + U_C + (size_t)(w * 16 + col) * 256 + kf * 32 + q * 8);
      cb = *(const f32x4*)(C_b + w * 16 + q * 4);
    }

    for (int i = 0; i < T_FWD; ++i) {
      __syncthreads();  // h_i (hbuf[cur]) and x_i (ibuf[cur]) visible
      // prefetch issued after the barrier (see encoder loop comment)
      f32x4 nv;
      if (i < T_FWD - 1 && xhalf)
        nv = *(const f32x4*)(fwd_x + ((size_t)(i + 1) * BATCHN + r0 + srow) * 64 + sc4 * 4);
      const unsigned short* hc = hbuf[cur];
      const unsigned short* ic = ibuf[cur];
      short8 bfr[10];
#pragma unroll
      for (int kf = 0; kf < 8; ++kf)
        bfr[kf] = *(const short8*)&hc[col * HP + kf * 32 + q * 8];
#pragma unroll
      for (int kf = 8; kf < 10; ++kf)
        bfr[kf] = *(const short8*)&ic[col * IP + (kf - 8) * 32 + q * 8];
      f32x4 acc[2];
#pragma unroll
      for (int mt = 0; mt < 2; ++mt) acc[mt] = bs[mt];
#pragma unroll
      for (int kf = 0; kf < 10; ++kf)
#pragma unroll
        for (int mt = 0; mt < 2; ++mt)
          acc[mt] = __builtin_amdgcn_mfma_f32_16x16x32_bf16(sf[mt][kf], bfr[kf], acc[mt], 0, 0, 0);
      if (w < 4 && i >= 1) {  // y_i = C h_i + C_b (h_i = this step's B-frags)
        f32x4 y = cb;
#pragma unroll
        for (int kf = 0; kf < 8; ++kf)
          y = __builtin_amdgcn_mfma_f32_16x16x32_bf16(cf[kf], bfr[kf], y, 0, 0, 0);
        *(f32x4*)(out + ((size_t)(i - 1) * BATCHN + r0 + col) * 64 + w * 16 + q * 4) = y;
      }
      unsigned short* hn_ = hbuf[cur ^ 1];
#pragma unroll
      for (int mt = 0; mt < 2; ++mt)
        *(uint2*)&hn_[col * HP + w * 32 + mt * 16 + q * 4] =
            make_uint2(pk(acc[mt][0], acc[mt][1]), pk(acc[mt][2], acc[mt][3]));
      if (i < T_FWD - 1 && xhalf)
        *(uint2*)&ibuf[cur ^ 1][srow * IP + sc4 * 4] =
            make_uint2(pk(nv[0], nv[1]), pk(nv[2], nv[3]));
      cur ^= 1;
    }

    // epilogue: y_80 from h_80
    __syncthreads();
    if (w < 4) {
      const unsigned short* hc = hbuf[cur];
      short8 bfr[8];
#pragma unroll
      for (int kf = 0; kf < 8; ++kf)
        bfr[kf] = *(const short8*)&hc[col * HP + kf * 32 + q * 8];
      f32x4 y = cb;
#pragma unroll
      for (int kf = 0; kf < 8; ++kf)
        y = __builtin_amdgcn_mfma_f32_16x16x32_bf16(cf[kf], bfr[kf], y, 0, 0, 0);
      *(f32x4*)(out + ((size_t)(T_FWD - 1) * BATCHN + r0 + col) * 64 + w * 16 + q * 4) = y;
    }
  }
}

extern "C" void kernel_launch(void* const* d_in, const int* in_sizes, int n_in,
                              void* d_out, int out_size, void* d_ws, size_t ws_size,
                              hipStream_t stream) {
  const float* pre_x = (const float*)d_in[0];
  const float* pre_y = (const float*)d_in[1];
  const float* fwd_x = (const float*)d_in[2];
  const float* A_w   = (const float*)d_in[3];
  const float* A_b   = (const float*)d_in[4];
  const float* B_w   = (const float*)d_in[5];
  const float* B_b   = (const float*)d_in[6];
  const float* C_w   = (const float*)d_in[7];
  const float* C_b   = (const float*)d_in[8];
  const float* W_ih  = (const float*)d_in[9];
  const float* b_ih  = (const float*)d_in[10];
  const float* W_hh  = (const float*)d_in[11];
  const float* b_hh  = (const float*)d_in[12];
  unsigned short* ws = (unsigned short*)d_ws;
  float* out = (float*)d_out;

  prep_kernel<<<(PREP_N + 255) / 256, 256, 0, stream>>>(
      A_w, A_b, B_w, B_b, C_w, W_ih, b_ih, W_hh, b_hh, ws);
  rnn_ss_kernel<<<BATCHN / 16, 512, 0, stream>>>(pre_x, pre_y, fwd_x, C_b, ws, out);
}

// Round 3
// 304.850 us; speedup vs baseline: 1.0983x; 1.0600x over previous
//
#include <hip/hip_runtime.h>
#include <hip/hip_bf16.h>

typedef __attribute__((ext_vector_type(8))) short short8;
typedef __attribute__((ext_vector_type(4))) float f32x4;

#define T_PRE 64
#define T_FWD 80
#define BATCHN 4096

#define HP 264   // h row pitch (bf16 elems): 256 + 8 pad
#define IP 136   // input row pitch: 128 + 8 pad

// ---- ws layout (ushort offsets) ----
// wrnn [256][384] bf16 : rows j = [W_hh[j] | W_ih[j]]
// wrec [256][384] bf16 : rows j = [A^2[j] | (A*B)[j] | B[j]]     (2-step SS)
// ywt  [2][64][384] bf16: i=0 rows o=[CA | CB | 0], i=1 [CA^2 | CAB | CB]
// f32: brnn[256]=b_ih+b_hh, brec[256]=(A+I)(A_b+B_b), yb[2][64]
// f32 scratch: CA[64][256] (prep1 -> prep2)
#define U_WRNN 0
#define U_WREC 98304
#define U_YW   196608
#define U_FB   245760
#define U_CAF  247040
#define PREP1_N 213504
#define PREP2_N 49280

__device__ __forceinline__ unsigned short bf1(float a) {
  unsigned ua = __float_as_uint(a);
  return (unsigned short)((ua + 0x7fffu + ((ua >> 16) & 1u)) >> 16);
}
__device__ __forceinline__ unsigned pk(float a, float b) {
  __hip_bfloat162 h = __float22bfloat162_rn(make_float2(a, b));
  unsigned u;
  __builtin_memcpy(&u, &h, 4);
  return u;
}
__device__ __forceinline__ float tanh_fast(float x) {
  float e = __expf(2.0f * x);  // saturates correctly for large |x|
  return 1.0f - 2.0f * __builtin_amdgcn_rcpf(e + 1.0f);
}

// prep1: wrnn copy, brnn, CA (f32 scratch), wrec (A^2 | AB | B), brec
__global__ void prep1_kernel(const float* __restrict__ A_w, const float* __restrict__ A_b,
                             const float* __restrict__ B_w, const float* __restrict__ B_b,
                             const float* __restrict__ W_ih, const float* __restrict__ b_ih,
                             const float* __restrict__ W_hh, const float* __restrict__ b_hh,
                             const float* __restrict__ C_w,
                             unsigned short* __restrict__ ws) {
  int i = blockIdx.x * 256 + threadIdx.x;
  float* fb = (float*)(ws + U_FB);
  float* caf = (float*)(ws + U_CAF);
  if (i < 98304) {
    int j = i / 384, k = i - j * 384;
    float v = (k < 256) ? W_hh[j * 256 + k] : W_ih[j * 128 + (k - 256)];
    ws[U_WRNN + i] = bf1(v);
  } else if (i < 98560) {
    int j = i - 98304;
    fb[j] = b_ih[j] + b_hh[j];
  } else if (i < 114944) {
    int ii = i - 98560;
    int o = ii >> 8, j = ii & 255;
    float s = 0.f;
    for (int k = 0; k < 256; ++k) s += C_w[o * 256 + k] * A_w[k * 256 + j];
    caf[ii] = s;
  } else if (i < 213248) {
    int ii = i - 114944;
    int j = ii / 384, k = ii - j * 384;
    float v;
    if (k < 256) {
      float s = 0.f;
      for (int kk = 0; kk < 256; ++kk) s += A_w[j * 256 + kk] * A_w[kk * 256 + k];
      v = s;
    } else if (k < 320) {
      int k2 = k - 256;
      float s = 0.f;
      for (int kk = 0; kk < 256; ++kk) s += A_w[j * 256 + kk] * B_w[kk * 64 + k2];
      v = s;
    } else {
      v = B_w[j * 64 + (k - 320)];
    }
    ws[U_WREC + ii] = bf1(v);
  } else if (i < PREP1_N) {
    int j = i - 213248;
    float s = A_b[j] + B_b[j];
    for (int k = 0; k < 256; ++k) s += A_w[j * 256 + k] * (A_b[k] + B_b[k]);
    fb[256 + j] = s;
  }
}

// prep2: ywt (needs CA from prep1), yb
__global__ void prep2_kernel(const float* __restrict__ A_w, const float* __restrict__ A_b,
                             const float* __restrict__ B_w, const float* __restrict__ B_b,
                             const float* __restrict__ C_w, const float* __restrict__ C_b,
                             unsigned short* __restrict__ ws) {
  int i = blockIdx.x * 256 + threadIdx.x;
  float* fb = (float*)(ws + U_FB);
  const float* caf = (const float*)(ws + U_CAF);
  if (i < 24576) {  // ywt i=0: [CA | CB | 0]
    int o = i / 384, k = i - o * 384;
    float v = 0.f;
    if (k < 256) {
      v = caf[o * 256 + k];
    } else if (k < 320) {
      int k2 = k - 256;
      float s = 0.f;
      for (int kk = 0; kk < 256; ++kk) s += C_w[o * 256 + kk] * B_w[kk * 64 + k2];
      v = s;
    }
    ws[U_YW + i] = bf1(v);
  } else if (i < 49152) {  // ywt i=1: [CA^2 | CAB | CB]
    int ii = i - 24576;
    int o = ii / 384, k = ii - o * 384;
    float v;
    if (k < 256) {
      float s = 0.f;
      for (int kk = 0; kk < 256; ++kk) s += caf[o * 256 + kk] * A_w[kk * 256 + k];
      v = s;
    } else if (k < 320) {
      int k2 = k - 256;
      float s = 0.f;
      for (int kk = 0; kk < 256; ++kk) s += caf[o * 256 + kk] * B_w[kk * 64 + k2];
      v = s;
    } else {
      int k2 = k - 320;
      float s = 0.f;
      for (int kk = 0; kk < 256; ++kk) s += C_w[o * 256 + kk] * B_w[kk * 64 + k2];
      v = s;
    }
    ws[U_YW + 24576 + ii] = bf1(v);
  } else if (i < PREP2_N) {  // yb[2][64]
    int ii = i - 49152;
    int o = ii & 63, which = ii >> 6;
    float s = C_b[o];
    if (which == 0) {
      for (int k = 0; k < 256; ++k) s += C_w[o * 256 + k] * (A_b[k] + B_b[k]);
    } else {
      for (int k = 0; k < 256; ++k)
        s += (caf[o * 256 + k] + C_w[o * 256 + k]) * (A_b[k] + B_b[k]);
    }
    fb[512 + which * 64 + o] = s;
  }
}

// Persistent: 256 blocks x 16 batch rows, 512 threads (8 waves, 2/SIMD).
// Encoder: round-0 structure (prefetch issued BEFORE barrier -> compiler hoists
// it above previous step's compute; full-step latency cover).
// SS phase: 2-step unrolled. Per k-block (2 time steps): one barrier, one h
// round-trip, one shared bfr=[h|x1|x2] (12 frags) feeding 3 MFMA chains
// (2 rec tiles + 1 y tile per wave; waves 0-3 -> y_{2b+1}, waves 4-7 -> y_{2b+2}).
__global__ __launch_bounds__(512, 1) void rnn_ss_kernel(
    const float* __restrict__ pre_x, const float* __restrict__ pre_y,
    const float* __restrict__ fwd_x,
    const unsigned short* __restrict__ ws, float* __restrict__ out) {
  __shared__ unsigned short hbuf[2][16 * HP];
  __shared__ unsigned short ibuf[2][16 * IP];

  const int tid = threadIdx.x;
  const int lane = tid & 63;
  const int w = tid >> 6;      // wave 0..7
  const int col = lane & 15;   // batch col (B/D) / A row-in-tile
  const int q = lane >> 4;     // quad
  const int r0 = blockIdx.x * 16;
  const int srow = (tid & 255) >> 4;  // staging batch row 0..15
  const int sc4 = tid & 15;           // staging float4 col 0..15
  const bool xhalf = (tid >= 256);    // waves 4-7 stage x (and x1); 0-3 stage y (and x2)

  // zero hbuf[0] h region -> h0 = 0
#pragma unroll
  for (int it = 0; it < 2; ++it) {
    int i = tid + it * 512;
    int r = i >> 6, c = (i & 63) * 4;
    *(uint2*)&hbuf[0][r * HP + c] = make_uint2(0u, 0u);
  }

  const float* fbias = (const float*)(ws + U_FB);
  int cur = 0;

  // ---------------- encoder tanh-RNN (K = 384) ----------------
  {
    short8 wf[2][12];
#pragma unroll
    for (int mt = 0; mt < 2; ++mt)
#pragma unroll
      for (int kf = 0; kf < 12; ++kf)
        wf[mt][kf] = *(const short8*)(ws + U_WRNN +
                       (size_t)(w * 32 + mt * 16 + col) * 384 + kf * 32 + q * 8);
    f32x4 br[2];
#pragma unroll
    for (int mt = 0; mt < 2; ++mt)
      br[mt] = *(const f32x4*)(fbias + w * 32 + mt * 16 + q * 4);

    // stage xy_0 into ibuf[0]
    {
      f32x4 v = xhalf ? *(const f32x4*)(pre_x + (size_t)(r0 + srow) * 64 + sc4 * 4)
                      : *(const f32x4*)(pre_y + (size_t)(r0 + srow) * 64 + sc4 * 4);
      *(uint2*)&ibuf[0][srow * IP + (xhalf ? 0 : 64) + sc4 * 4] =
          make_uint2(pk(v[0], v[1]), pk(v[2], v[3]));
    }

    for (int t = 0; t < T_PRE; ++t) {
      f32x4 nv;
      if (t < T_PRE - 1) {
        nv = xhalf ? *(const f32x4*)(pre_x + ((size_t)(t + 1) * BATCHN + r0 + srow) * 64 + sc4 * 4)
                   : *(const f32x4*)(pre_y + ((size_t)(t + 1) * BATCHN + r0 + srow) * 64 + sc4 * 4);
      } else {
        // hand off to SS: stage fwd_x[0] at [0,64) and fwd_x[1] at [64,128)
        nv = xhalf ? *(const f32x4*)(fwd_x + (size_t)(r0 + srow) * 64 + sc4 * 4)
                   : *(const f32x4*)(fwd_x + ((size_t)BATCHN + r0 + srow) * 64 + sc4 * 4);
      }
      __syncthreads();  // h_t (hbuf[cur]) and xy_t (ibuf[cur]) visible
      const unsigned short* hc = hbuf[cur];
      const unsigned short* ic = ibuf[cur];
      short8 bfr[12];
#pragma unroll
      for (int kf = 0; kf < 8; ++kf)
        bfr[kf] = *(const short8*)&hc[col * HP + kf * 32 + q * 8];
#pragma unroll
      for (int kf = 8; kf < 12; ++kf)
        bfr[kf] = *(const short8*)&ic[col * IP + (kf - 8) * 32 + q * 8];
      f32x4 acc[2];
#pragma unroll
      for (int mt = 0; mt < 2; ++mt) acc[mt] = br[mt];
#pragma unroll
      for (int kf = 0; kf < 12; ++kf)
#pragma unroll
        for (int mt = 0; mt < 2; ++mt)
          acc[mt] = __builtin_amdgcn_mfma_f32_16x16x32_bf16(wf[mt][kf], bfr[kf], acc[mt], 0, 0, 0);
      unsigned short* hn_ = hbuf[cur ^ 1];
#pragma unroll
      for (int mt = 0; mt < 2; ++mt) {
        float t0 = tanh_fast(acc[mt][0]), t1 = tanh_fast(acc[mt][1]);
        float t2 = tanh_fast(acc[mt][2]), t3 = tanh_fast(acc[mt][3]);
        *(uint2*)&hn_[col * HP + w * 32 + mt * 16 + q * 4] =
            make_uint2(pk(t0, t1), pk(t2, t3));
      }
      *(uint2*)&ibuf[cur ^ 1][srow * IP + (xhalf ? 0 : 64) + sc4 * 4] =
          make_uint2(pk(nv[0], nv[1]), pk(nv[2], nv[3]));
      cur ^= 1;
    }
  }

  // -------- state-space rollout, 2-step unrolled (K = 384) + fused y --------
  {
    short8 rf[2][12];
#pragma unroll
    for (int mt = 0; mt < 2; ++mt)
#pragma unroll
      for (int kf = 0; kf < 12; ++kf)
        rf[mt][kf] = *(const short8*)(ws + U_WREC +
                       (size_t)(w * 32 + mt * 16 + col) * 384 + kf * 32 + q * 8);
    f32x4 brv[2];
#pragma unroll
    for (int mt = 0; mt < 2; ++mt)
      brv[mt] = *(const f32x4*)(fbias + 256 + w * 32 + mt * 16 + q * 4);

    const int yi = w >> 2;   // 0 -> y_{2b+1}, 1 -> y_{2b+2}
    const int yc = w & 3;    // out-dim 16-block
    short8 yf[12];
#pragma unroll
    for (int kf = 0; kf < 12; ++kf)
      yf[kf] = *(const short8*)(ws + U_YW +
                 (size_t)(yi * 64 + yc * 16 + col) * 384 + kf * 32 + q * 8);
    f32x4 ybv = *(const f32x4*)(fbias + 512 + yi * 64 + yc * 16 + q * 4);

    for (int b = 0; b < T_FWD / 2; ++b) {
      f32x4 nv;
      const bool st = (b < T_FWD / 2 - 1);
      if (st)
        nv = *(const f32x4*)(fwd_x +
              ((size_t)(2 * b + 2 + (xhalf ? 0 : 1)) * BATCHN + r0 + srow) * 64 + sc4 * 4);
      __syncthreads();  // h_{2b} (hbuf[cur]) and x_{2b+1},x_{2b+2} (ibuf[cur]) visible
      const unsigned short* hc = hbuf[cur];
      const unsigned short* ic = ibuf[cur];
      short8 bfr[12];
#pragma unroll
      for (int kf = 0; kf < 8; ++kf)
        bfr[kf] = *(const short8*)&hc[col * HP + kf * 32 + q * 8];
#pragma unroll
      for (int kf = 8; kf < 12; ++kf)
        bfr[kf] = *(const short8*)&ic[col * IP + (kf - 8) * 32 + q * 8];
      f32x4 acc[2];
#pragma unroll
      for (int mt = 0; mt < 2; ++mt) acc[mt] = brv[mt];
      f32x4 yacc = ybv;
#pragma unroll
      for (int kf = 0; kf < 12; ++kf) {
        acc[0] = __builtin_amdgcn_mfma_f32_16x16x32_bf16(rf[0][kf], bfr[kf], acc[0], 0, 0, 0);
        acc[1] = __builtin_amdgcn_mfma_f32_16x16x32_bf16(rf[1][kf], bfr[kf], acc[1], 0, 0, 0);
        yacc   = __builtin_amdgcn_mfma_f32_16x16x32_bf16(yf[kf],    bfr[kf], yacc,   0, 0, 0);
      }
      *(f32x4*)(out + ((size_t)(2 * b + yi) * BATCHN + r0 + col) * 64 + yc * 16 + q * 4) = yacc;
      unsigned short* hn_ = hbuf[cur ^ 1];
#pragma unroll
      for (int mt = 0; mt < 2; ++mt)
        *(uint2*)&hn_[col * HP + w * 32 + mt * 16 + q * 4] =
            make_uint2(pk(acc[mt][0], acc[mt][1]), pk(acc[mt][2], acc[mt][3]));
      if (st)
        *(uint2*)&ibuf[cur ^ 1][srow * IP + (xhalf ? 0 : 64) + sc4 * 4] =
            make_uint2(pk(nv[0], nv[1]), pk(nv[2], nv[3]));
      cur ^= 1;
    }
  }
}

extern "C" void kernel_launch(void* const* d_in, const int* in_sizes, int n_in,
                              void* d_out, int out_size, void* d_ws, size_t ws_size,
                              hipStream_t stream) {
  const float* pre_x = (const float*)d_in[0];
  const float* pre_y = (const float*)d_in[1];
  const float* fwd_x = (const float*)d_in[2];
  const float* A_w   = (const float*)d_in[3];
  const float* A_b   = (const float*)d_in[4];
  const float* B_w   = (const float*)d_in[5];
  const float* B_b   = (const float*)d_in[6];
  const float* C_w   = (const float*)d_in[7];
  const float* C_b   = (const float*)d_in[8];
  const float* W_ih  = (const float*)d_in[9];
  const float* b_ih  = (const float*)d_in[10];
  const float* W_hh  = (const float*)d_in[11];
  const float* b_hh  = (const float*)d_in[12];
  unsigned short* ws = (unsigned short*)d_ws;
  float* out = (float*)d_out;

  prep1_kernel<<<(PREP1_N + 255) / 256, 256, 0, stream>>>(
      A_w, A_b, B_w, B_b, W_ih, b_ih, W_hh, b_hh, C_w, ws);
  prep2_kernel<<<(PREP2_N + 255) / 256, 256, 0, stream>>>(
      A_w, A_b, B_w, B_b, C_w, C_b, ws);
  rnn_ss_kernel<<<BATCHN / 16, 512, 0, stream>>>(pre_x, pre_y, fwd_x, ws, out);
}